// Round 3
// baseline (172.462 us; speedup 1.0000x reference)
//
#include <hip/hip_runtime.h>
#include <stdint.h>

// DETR post-process: per batch n of 256, top-300 of sigmoid(logits[n]) (80000
// elems), output [label, score, scaled box] per selected query.
//
// Ordering: jax top_k = score desc, tie -> lowest index. sigmoid is strictly
// monotonic, so we select/rank on 64-bit key (ord(logit)<<32 | ~index):
// descending key order == (score desc, index asc) exactly.
//
// R3 structure: one 1024-thread block per batch, TWO global scans (R1 evidence:
// the rescan is fully L2/L3-absorbed — FETCH_SIZE stayed at one input read).
// NO per-thread value caching (R2 evidence: vals[80] spilled to scratch,
// WRITE_SIZE 1.8->49 MB, net loss). Loads are grouped 5x float4 per batch to
// keep ~5 loads in flight per wave (ILP for HBM latency hiding).
//   1. scan 1: 2048-bin LDS histogram of top-11 ordered bits (4-way
//      lane-replicated atomics).
//   2. radix-select threshold T (refinement levels rescan global; never
//      triggered for normal data: level 0 yields ~500 candidates <= 2048).
//   3. scan 2: compact candidates (ord >= T) into LDS as u64 keys.
//   4. rank-by-count (LDS broadcast reads), rank<300 scatters its output row.

#define TOPK 300
#define NCLS 80
#define NQ 1000
#define QK (NQ * NCLS)   // 80000
#define NB 2048          // histogram bins (11 bits)
#define CAP 2048         // candidate buffer
#define THREADS 1024
#define LAST_VALID 544   // j=19: 4*t + 4096*19 < 80000  <=>  t < 544

typedef unsigned long long u64;

__device__ __forceinline__ uint32_t ordf(float f) {
  uint32_t u = __float_as_uint(f);
  return (u & 0x80000000u) ? ~u : (u | 0x80000000u);  // monotonic float->uint
}
__device__ __forceinline__ float unordf(uint32_t o) {
  uint32_t u = (o & 0x80000000u) ? (o & 0x7fffffffu) : ~o;
  return __uint_as_float(u);
}

__global__ __launch_bounds__(THREADS) void detr_post_kernel(
    const float* __restrict__ logits, const float* __restrict__ boxes,
    const int* __restrict__ osz, float* __restrict__ out) {
  __shared__ uint32_t hist4[NB * 4];  // 4-way replicated (t&3) histogram
  __shared__ uint32_t histf[NB];
  __shared__ u64 buf[CAP];
  __shared__ uint32_t sh_sel[3];  // {bin, suffix[bin+1], suffix[bin]}
  __shared__ uint32_t sh_cnt;

  const int n = blockIdx.x;
  const int t = threadIdx.x;
  const uint32_t sub = (uint32_t)(t & 3);
  const float* lg = logits + (size_t)n * QK;

  // ---- phase 1: histogram scan (groups of 5 coalesced float4 loads)
  for (int b = t; b < NB * 4; b += THREADS) hist4[b] = 0;
  __syncthreads();

#pragma unroll
  for (int g = 0; g < 4; ++g) {
    const int base = g * 5 * 4096 + 4 * t;
    float4 v[5];
    const bool has4 = (g < 3) || (t < LAST_VALID);
    v[0] = *(const float4*)(lg + base);
    v[1] = *(const float4*)(lg + base + 4096);
    v[2] = *(const float4*)(lg + base + 2 * 4096);
    v[3] = *(const float4*)(lg + base + 3 * 4096);
    if (has4) v[4] = *(const float4*)(lg + base + 4 * 4096);
    const int ns = has4 ? 5 : 4;
    for (int s = 0; s < ns; ++s) {
      atomicAdd(&hist4[((ordf(v[s].x) >> 21) << 2) | sub], 1u);
      atomicAdd(&hist4[((ordf(v[s].y) >> 21) << 2) | sub], 1u);
      atomicAdd(&hist4[((ordf(v[s].z) >> 21) << 2) | sub], 1u);
      atomicAdd(&hist4[((ordf(v[s].w) >> 21) << 2) | sub], 1u);
    }
  }

  // ---- phase 2: radix select. Level 0 from the histogram above; refinement
  // levels (adversarial data only) rescan global, which L2/L3 absorbs.
  uint32_t T = 0;
  uint32_t S_above = 0;
  uint32_t Krem = TOPK;
  int prev_shift = 32;

  const int shifts[3] = {21, 10, 0};
  const int nbns[3] = {2048, 2048, 1024};

  for (int lvl = 0; lvl < 3; ++lvl) {
    const int sh = shifts[lvl];
    const uint32_t nb = (uint32_t)nbns[lvl];

    if (lvl > 0) {
      for (int b = t; b < NB * 4; b += THREADS) hist4[b] = 0;
      __syncthreads();
      for (int j = 0; j < 20; ++j) {
        const int i = 4 * t + 4096 * j;
        if (j == 19 && t >= LAST_VALID) break;
        const float4 v = *(const float4*)(lg + i);
        const float vs[4] = {v.x, v.y, v.z, v.w};
        for (int c = 0; c < 4; ++c) {
          const uint32_t u = ordf(vs[c]);
          if ((u >> prev_shift) == (T >> prev_shift))
            atomicAdd(&hist4[(((u >> sh) & (nb - 1)) << 2) | sub], 1u);
        }
      }
    }
    __syncthreads();

    // fold the 4 replicas
    for (uint32_t b = t; b < nb; b += (uint32_t)THREADS) {
      const uint32_t i4 = b << 2;
      histf[b] = hist4[i4] + hist4[i4 + 1] + hist4[i4 + 2] + hist4[i4 + 3];
    }
    __syncthreads();

    // inclusive suffix sum: histf[b] = count(bin >= b)
    for (uint32_t off = 1; off < nb; off <<= 1) {
      uint32_t a0 = histf[t] + ((t + off < nb) ? histf[t + off] : 0u);
      uint32_t a1 = 0;
      if (nb > (uint32_t)THREADS) {
        const uint32_t i1 = (uint32_t)t + THREADS;
        a1 = histf[i1] + ((i1 + off < nb) ? histf[i1 + off] : 0u);
      }
      __syncthreads();
      histf[t] = a0;
      if (nb > (uint32_t)THREADS) histf[(uint32_t)t + THREADS] = a1;
      __syncthreads();
    }

    // threshold bin: suffix[b] >= Krem, suffix[b+1] < Krem (unique, monotone)
    for (uint32_t b = t; b < nb; b += (uint32_t)THREADS) {
      const uint32_t s = histf[b];
      const uint32_t sn = (b + 1 < nb) ? histf[b + 1] : 0u;
      if (s >= Krem && sn < Krem) {
        sh_sel[0] = b;
        sh_sel[1] = sn;
        sh_sel[2] = s;
      }
    }
    __syncthreads();
    const uint32_t bsel = sh_sel[0], above = sh_sel[1], candL = sh_sel[2];
    __syncthreads();  // sh_sel consumed before any next-level overwrite

    T |= bsel << sh;
    if (S_above + candL <= CAP || lvl == 2) break;
    S_above += above;
    Krem -= above;
    prev_shift = sh;
  }

  // ---- phase 3: rescan (L2/L3-resident), compact candidates into LDS
  if (t == 0) sh_cnt = 0;
  __syncthreads();
#pragma unroll
  for (int g = 0; g < 4; ++g) {
    const int base = g * 5 * 4096 + 4 * t;
    float4 v[5];
    const bool has4 = (g < 3) || (t < LAST_VALID);
    v[0] = *(const float4*)(lg + base);
    v[1] = *(const float4*)(lg + base + 4096);
    v[2] = *(const float4*)(lg + base + 2 * 4096);
    v[3] = *(const float4*)(lg + base + 3 * 4096);
    if (has4) v[4] = *(const float4*)(lg + base + 4 * 4096);
    const int ns = has4 ? 5 : 4;
    for (int s = 0; s < ns; ++s) {
      const float vs[4] = {v[s].x, v[s].y, v[s].z, v[s].w};
#pragma unroll
      for (int c = 0; c < 4; ++c) {
        const uint32_t u = ordf(vs[c]);
        if (u >= T) {
          const uint32_t p = atomicAdd(&sh_cnt, 1u);
          const uint32_t idx = (uint32_t)(base + s * 4096 + c);
          if (p < CAP)  // clamp reachable only for adversarial mass-tie input
            buf[p] = ((u64)u << 32) | (u64)(~idx);
        }
      }
    }
  }
  __syncthreads();
  const uint32_t cnt = sh_cnt < CAP ? sh_cnt : CAP;
  const uint32_t cnt4 = (cnt + 3u) & ~3u;
  for (uint32_t p = cnt + t; p < cnt4; p += (uint32_t)THREADS)
    buf[p] = 0ULL;  // pad for 4-wide rank loop; 0 < any real key
  __syncthreads();

  // ---- phase 4: rank by counting (LDS broadcast reads, conflict-free),
  // then direct scatter of the 300 winners
  const float s0 = (float)osz[0];
  const float s1 = (float)osz[1];
  for (uint32_t p = t; p < cnt; p += (uint32_t)THREADS) {
    const u64 my = buf[p];
    uint32_t rank = 0;
    for (uint32_t q = 0; q < cnt4; q += 4) {
      const u64 k0 = buf[q + 0], k1 = buf[q + 1];
      const u64 k2 = buf[q + 2], k3 = buf[q + 3];
      rank += (uint32_t)(k0 > my) + (uint32_t)(k1 > my) +
              (uint32_t)(k2 > my) + (uint32_t)(k3 > my);
    }
    if (rank < TOPK) {
      const uint32_t u = (uint32_t)(my >> 32);
      const uint32_t idx = ~(uint32_t)(my & 0xffffffffu);
      const float lgv = unordf(u);
      const float score = 1.0f / (1.0f + expf(-lgv));
      const uint32_t q = idx / NCLS;
      const uint32_t lab = idx - q * NCLS;
      const float* bp = boxes + ((size_t)n * NQ + q) * 4;
      const float cx = bp[0], cy = bp[1], w = bp[2], h = bp[3];
      float* op = out + ((size_t)n * TOPK + rank) * 6;
      op[0] = (float)lab;
      op[1] = score;
      op[2] = (cx - 0.5f * w) * s1;
      op[3] = (cy - 0.5f * h) * s0;
      op[4] = w * s1;
      op[5] = h * s0;
    }
  }
}

extern "C" void kernel_launch(void* const* d_in, const int* in_sizes, int n_in,
                              void* d_out, int out_size, void* d_ws, size_t ws_size,
                              hipStream_t stream) {
  const float* logits = (const float*)d_in[0];
  const float* boxes = (const float*)d_in[1];
  const int* osz = (const int*)d_in[2];
  float* out = (float*)d_out;
  const int nbatch = in_sizes[0] / QK;  // 256
  detr_post_kernel<<<nbatch, THREADS, 0, stream>>>(logits, boxes, osz, out);
}

// Round 4
// 132.269 us; speedup vs baseline: 1.3039x; 1.3039x over previous
//
#include <hip/hip_runtime.h>
#include <stdint.h>

// DETR post-process: per batch n of 256, top-300 of sigmoid(logits[n]) (80000
// elems), output [label, score, scaled box] per selected query.
//
// Ordering: jax top_k = score desc, tie -> lowest index. sigmoid is strictly
// monotonic, so we rank on 64-bit key (ord(logit)<<32 | ~index): descending
// key order == (score desc, index asc) exactly.
//
// R4 structure: one 1024-thread block per batch, ONE streaming scan.
//   Fast path: compact all logits >= 2.4f straight into LDS (~650 expected
//   for N(0,1) data; bounds [300, 2048] are 14+ sigma safe). Verified
//   in-kernel: if cnt outside [TOPK, CAP], run a full radix-select fallback
//   (correct for arbitrary data, never taken for the bench input).
//   Then rank-by-count (LDS broadcast) and scatter the 300 winners.
//
// Hard-learned rules: NO per-thread arrays with runtime indexing (R2/R3:
// scratch spill, WRITE_SIZE 49/161 MB). All load indices compile-time affine.

#define TOPK 300
#define NCLS 80
#define NQ 1000
#define QK (NQ * NCLS)   // 80000
#define NB 2048
#define CAP 2048
#define THREADS 1024
#define LAST_VALID 544   // j=19: 4*t + 4096*19 < 80000  <=>  t < 544
#define T0F 2.4f         // fixed fast-path threshold (z-score)

typedef unsigned long long u64;

__device__ __forceinline__ uint32_t ordf(float f) {
  uint32_t u = __float_as_uint(f);
  return (u & 0x80000000u) ? ~u : (u | 0x80000000u);  // monotonic float->uint
}
__device__ __forceinline__ float unordf(uint32_t o) {
  uint32_t u = (o & 0x80000000u) ? (o & 0x7fffffffu) : ~o;
  return __uint_as_float(u);
}

__global__ __launch_bounds__(THREADS) void detr_post_kernel(
    const float* __restrict__ logits, const float* __restrict__ boxes,
    const int* __restrict__ osz, float* __restrict__ out) {
  __shared__ uint32_t hist4[NB * 4];  // fallback only
  __shared__ uint32_t histf[NB];      // fallback only
  __shared__ u64 buf[CAP];
  __shared__ uint32_t sh_sel[3];
  __shared__ uint32_t sh_cnt;

  const int n = blockIdx.x;
  const int t = threadIdx.x;
  const float* lg = logits + (size_t)n * QK;

  // ---- fast path: single streaming scan, compact x >= T0F into LDS.
  // ~650 atomics per block total (rare branch), pure-streaming loads.
  if (t == 0) sh_cnt = 0;
  __syncthreads();

#pragma unroll 5
  for (int j = 0; j < 19; ++j) {
    const int i = 4 * t + 4096 * j;
    const float4 v = *(const float4*)(lg + i);
    if (v.x >= T0F) {
      const uint32_t p = atomicAdd(&sh_cnt, 1u);
      if (p < CAP) buf[p] = ((u64)ordf(v.x) << 32) | (u64)(~(uint32_t)(i + 0));
    }
    if (v.y >= T0F) {
      const uint32_t p = atomicAdd(&sh_cnt, 1u);
      if (p < CAP) buf[p] = ((u64)ordf(v.y) << 32) | (u64)(~(uint32_t)(i + 1));
    }
    if (v.z >= T0F) {
      const uint32_t p = atomicAdd(&sh_cnt, 1u);
      if (p < CAP) buf[p] = ((u64)ordf(v.z) << 32) | (u64)(~(uint32_t)(i + 2));
    }
    if (v.w >= T0F) {
      const uint32_t p = atomicAdd(&sh_cnt, 1u);
      if (p < CAP) buf[p] = ((u64)ordf(v.w) << 32) | (u64)(~(uint32_t)(i + 3));
    }
  }
  if (t < LAST_VALID) {
    const int i = 4 * t + 4096 * 19;
    const float4 v = *(const float4*)(lg + i);
    if (v.x >= T0F) {
      const uint32_t p = atomicAdd(&sh_cnt, 1u);
      if (p < CAP) buf[p] = ((u64)ordf(v.x) << 32) | (u64)(~(uint32_t)(i + 0));
    }
    if (v.y >= T0F) {
      const uint32_t p = atomicAdd(&sh_cnt, 1u);
      if (p < CAP) buf[p] = ((u64)ordf(v.y) << 32) | (u64)(~(uint32_t)(i + 1));
    }
    if (v.z >= T0F) {
      const uint32_t p = atomicAdd(&sh_cnt, 1u);
      if (p < CAP) buf[p] = ((u64)ordf(v.z) << 32) | (u64)(~(uint32_t)(i + 2));
    }
    if (v.w >= T0F) {
      const uint32_t p = atomicAdd(&sh_cnt, 1u);
      if (p < CAP) buf[p] = ((u64)ordf(v.w) << 32) | (u64)(~(uint32_t)(i + 3));
    }
  }
  __syncthreads();

  uint32_t cnt = sh_cnt;
  const bool fast_ok = (cnt >= TOPK && cnt <= CAP);  // block-uniform

  if (!fast_ok) {
    // ---- fallback: full radix select on ord(logit), then recompact.
    // Correct for arbitrary inputs; never taken for the bench distribution.
    uint32_t T = 0, S_above = 0, Krem = TOPK;
    int prev_shift = 32;
    const uint32_t sub = (uint32_t)(t & 3);
    const int shifts[3] = {21, 10, 0};
    const int nbns[3] = {2048, 2048, 1024};

    for (int lvl = 0; lvl < 3; ++lvl) {
      const int sh = shifts[lvl];
      const uint32_t nb = (uint32_t)nbns[lvl];

      for (int b = t; b < NB * 4; b += THREADS) hist4[b] = 0;
      __syncthreads();
      for (int j = 0; j < 20; ++j) {
        if (j == 19 && t >= LAST_VALID) break;
        const int i = 4 * t + 4096 * j;
        const float4 v = *(const float4*)(lg + i);
        const float vs[4] = {v.x, v.y, v.z, v.w};
        for (int c = 0; c < 4; ++c) {
          const uint32_t u = ordf(vs[c]);
          if (lvl == 0 || (u >> prev_shift) == (T >> prev_shift))
            atomicAdd(&hist4[(((u >> sh) & (nb - 1)) << 2) | sub], 1u);
        }
      }
      __syncthreads();

      for (uint32_t b = t; b < nb; b += (uint32_t)THREADS) {
        const uint32_t i4 = b << 2;
        histf[b] = hist4[i4] + hist4[i4 + 1] + hist4[i4 + 2] + hist4[i4 + 3];
      }
      __syncthreads();

      for (uint32_t off = 1; off < nb; off <<= 1) {
        uint32_t a0 = histf[t] + ((t + off < nb) ? histf[t + off] : 0u);
        uint32_t a1 = 0;
        if (nb > (uint32_t)THREADS) {
          const uint32_t i1 = (uint32_t)t + THREADS;
          a1 = histf[i1] + ((i1 + off < nb) ? histf[i1 + off] : 0u);
        }
        __syncthreads();
        histf[t] = a0;
        if (nb > (uint32_t)THREADS) histf[(uint32_t)t + THREADS] = a1;
        __syncthreads();
      }

      for (uint32_t b = t; b < nb; b += (uint32_t)THREADS) {
        const uint32_t s = histf[b];
        const uint32_t sn = (b + 1 < nb) ? histf[b + 1] : 0u;
        if (s >= Krem && sn < Krem) {
          sh_sel[0] = b;
          sh_sel[1] = sn;
          sh_sel[2] = s;
        }
      }
      __syncthreads();
      const uint32_t bsel = sh_sel[0], above = sh_sel[1], candL = sh_sel[2];
      __syncthreads();

      T |= bsel << sh;
      if (S_above + candL <= CAP || lvl == 2) break;
      S_above += above;
      Krem -= above;
      prev_shift = sh;
    }

    // recompact with the radix-derived ordered threshold
    if (t == 0) sh_cnt = 0;
    __syncthreads();
    for (int j = 0; j < 20; ++j) {
      if (j == 19 && t >= LAST_VALID) break;
      const int i = 4 * t + 4096 * j;
      const float4 v = *(const float4*)(lg + i);
      const float vs[4] = {v.x, v.y, v.z, v.w};
      for (int c = 0; c < 4; ++c) {
        const uint32_t u = ordf(vs[c]);
        if (u >= T) {
          const uint32_t p = atomicAdd(&sh_cnt, 1u);
          if (p < CAP) buf[p] = ((u64)u << 32) | (u64)(~(uint32_t)(i + c));
        }
      }
    }
    __syncthreads();
    cnt = sh_cnt < CAP ? sh_cnt : CAP;
  }

  // ---- pad to multiple of 4 for the rank loop (0 sorts below any real key)
  const uint32_t cnt4 = (cnt + 3u) & ~3u;
  for (uint32_t p = cnt + t; p < cnt4; p += (uint32_t)THREADS) buf[p] = 0ULL;
  __syncthreads();

  // ---- rank by counting (LDS broadcast reads, conflict-free), scatter
  const float s0 = (float)osz[0];
  const float s1 = (float)osz[1];
  for (uint32_t p = t; p < cnt; p += (uint32_t)THREADS) {
    const u64 my = buf[p];
    uint32_t rank = 0;
    for (uint32_t q = 0; q < cnt4; q += 4) {
      const u64 k0 = buf[q + 0], k1 = buf[q + 1];
      const u64 k2 = buf[q + 2], k3 = buf[q + 3];
      rank += (uint32_t)(k0 > my) + (uint32_t)(k1 > my) +
              (uint32_t)(k2 > my) + (uint32_t)(k3 > my);
    }
    if (rank < TOPK) {
      const uint32_t u = (uint32_t)(my >> 32);
      const uint32_t idx = ~(uint32_t)(my & 0xffffffffu);
      const float lgv = unordf(u);
      const float score = 1.0f / (1.0f + expf(-lgv));
      const uint32_t q = idx / NCLS;
      const uint32_t lab = idx - q * NCLS;
      const float* bp = boxes + ((size_t)n * NQ + q) * 4;
      const float cx = bp[0], cy = bp[1], w = bp[2], h = bp[3];
      float* op = out + ((size_t)n * TOPK + rank) * 6;
      op[0] = (float)lab;
      op[1] = score;
      op[2] = (cx - 0.5f * w) * s1;
      op[3] = (cy - 0.5f * h) * s0;
      op[4] = w * s1;
      op[5] = h * s0;
    }
  }
}

extern "C" void kernel_launch(void* const* d_in, const int* in_sizes, int n_in,
                              void* d_out, int out_size, void* d_ws, size_t ws_size,
                              hipStream_t stream) {
  const float* logits = (const float*)d_in[0];
  const float* boxes = (const float*)d_in[1];
  const int* osz = (const int*)d_in[2];
  float* out = (float*)d_out;
  const int nbatch = in_sizes[0] / QK;  // 256
  detr_post_kernel<<<nbatch, THREADS, 0, stream>>>(logits, boxes, osz, out);
}